// Round 3
// baseline (176.598 us; speedup 1.0000x reference)
//
#include <hip/hip_runtime.h>
#include <hip/hip_cooperative_groups.h>

namespace cg = cooperative_groups;

#define EPS 1e-7f
#define LOG2E 1.44269504088896340736f

constexpr int SEGS  = 32;   // i-split; grid = 32x32 = 1024 blocks = 4 blocks/CU (co-resident)
constexpr int BLOCK = 256;

// Single cooperative kernel: phase 1 computes per-segment partial (num, den),
// grid-wide sync, phase 2 reduces segments and normalizes.
//
// Math: w = exp(-d2/(2b^2)) = exp2(k*d2), k = -log2(e)/(2b^2) < 0.
// With r = sqrt(-k):  k*d2 = -((r*px - r*x0)^2 + (r*py - r*y0)^2)
// -> inner loop: 2 fma + 1 mul + 1 fma + exp2(-t) [neg is a free src modifier]
//    + 1 fma + 1 add = 7 VALU-class instructions per pair.
__global__ __launch_bounds__(BLOCK, 4) void nw_fused(
    const float2* __restrict__ x,        // M x 2 query points
    const float2* __restrict__ inputs,   // N x 2 data points
    const float*  __restrict__ outputs,  // N
    const float*  __restrict__ bw,       // M
    float2*       __restrict__ partial,  // SEGS x M  (num, den) in d_ws
    float*        __restrict__ out,      // M
    int N, int M)
{
    cg::grid_group grid = cg::this_grid();

    const int j   = blockIdx.x * BLOCK + threadIdx.x;
    const int seg = blockIdx.y;
    const int per = (N + SEGS - 1) / SEGS;
    const int i0  = seg * per;
    const int i1  = min(N, i0 + per);

    float r = 0.f, rx0 = 0.f, ry0 = 0.f;
    if (j < M) {
        float2 xj = x[j];
        float  b  = bw[j];
        r   = sqrtf(LOG2E / (2.0f * b * b));   // = sqrt(-k)
        rx0 = r * xj.x;
        ry0 = r * xj.y;
    }

    // two accumulator pairs -> ILP / v_pk_fma_f32 opportunity
    float num0 = 0.f, num1 = 0.f, den0 = 0.f, den1 = 0.f;
    int i = i0;
    #pragma unroll 4
    for (; i + 1 < i1; i += 2) {
        float2 pa = inputs[i];       // block-uniform address -> scalar load
        float2 pb = inputs[i + 1];
        float  oa = outputs[i];
        float  ob = outputs[i + 1];
        float dxa = fmaf(r, pa.x, -rx0);
        float dya = fmaf(r, pa.y, -ry0);
        float dxb = fmaf(r, pb.x, -rx0);
        float dyb = fmaf(r, pb.y, -ry0);
        float ta  = fmaf(dxa, dxa, dya * dya);
        float tb  = fmaf(dxb, dxb, dyb * dyb);
        float wa  = __builtin_amdgcn_exp2f(-ta);   // neg folds into v_exp_f32
        float wb  = __builtin_amdgcn_exp2f(-tb);
        num0 = fmaf(wa, oa, num0);
        num1 = fmaf(wb, ob, num1);
        den0 += wa;
        den1 += wb;
    }
    if (i < i1) {
        float2 pa = inputs[i];
        float  oa = outputs[i];
        float dxa = fmaf(r, pa.x, -rx0);
        float dya = fmaf(r, pa.y, -ry0);
        float ta  = fmaf(dxa, dxa, dya * dya);
        float wa  = __builtin_amdgcn_exp2f(-ta);
        num0 = fmaf(wa, oa, num0);
        den0 += wa;
    }

    if (j < M) partial[(size_t)seg * M + j] = make_float2(num0 + num1, den0 + den1);

    grid.sync();   // execution + memory barrier across the grid

    if (seg == 0 && j < M) {
        float num = 0.f, den = 0.f;
        #pragma unroll
        for (int s = 0; s < SEGS; ++s) {
            float2 p = partial[(size_t)s * M + j];   // coalesced across j
            num += p.x;
            den += p.y;
        }
        out[j] = num / (den + EPS);
    }
}

extern "C" void kernel_launch(void* const* d_in, const int* in_sizes, int n_in,
                              void* d_out, int out_size, void* d_ws, size_t ws_size,
                              hipStream_t stream) {
    // setup_inputs() dict order: x (M*2), inputs (N*2), outputs (N), bandwidth (M)
    const float2* x       = (const float2*)d_in[0];
    const float2* inputs  = (const float2*)d_in[1];
    const float*  outputs = (const float*) d_in[2];
    const float*  bwv     = (const float*) d_in[3];
    int N = in_sizes[2];   // outputs element count
    int M = in_sizes[3];   // bandwidth element count
    float*        out     = (float*)d_out;
    float2*       partial = (float2*)d_ws;   // SEGS * M * 8 B = 2 MB

    dim3 grid((M + BLOCK - 1) / BLOCK, SEGS);
    dim3 block(BLOCK);
    void* args[] = { (void*)&x, (void*)&inputs, (void*)&outputs, (void*)&bwv,
                     (void*)&partial, (void*)&out, (void*)&N, (void*)&M };
    hipLaunchCooperativeKernel((const void*)nw_fused, grid, block, args, 0, stream);
}

// Round 4
// 77.339 us; speedup vs baseline: 2.2834x; 2.2834x over previous
//
#include <hip/hip_runtime.h>

#define EPS 1e-7f
#define LOG2E 1.44269504088896340736f

constexpr int SEGS  = 64;   // i-split: 2048 blocks = 8 blocks/CU = 32 waves/CU (full occupancy)
constexpr int BLOCK = 256;

// Kernel 1: each thread owns one output j and a segment of the i-loop.
// w = exp(-d2/(2b^2)) = exp2(-((r*px - rx0)^2 + (r*py - ry0)^2)), r = sqrt(log2e/(2b^2))
// Inner loop: 2 fma + mul + fma + exp2(-t) [neg = free src modifier] + fma + add
// = 7 VALU-class ops/pair. i is block-uniform -> loads scalarize (s_load),
// and unroll-8 lets the compiler batch them into wide s_load_dwordx8/x16.
__global__ __launch_bounds__(BLOCK) void nw_partial(
    const float2* __restrict__ x,        // M x 2 query points
    const float2* __restrict__ inputs,   // N x 2 data points
    const float*  __restrict__ outputs,  // N
    const float*  __restrict__ bw,       // M
    float2*       __restrict__ partial,  // SEGS x M  (num, den)
    int N, int M)
{
    const int j   = blockIdx.x * BLOCK + threadIdx.x;
    const int seg = blockIdx.y;
    const int per = (N + SEGS - 1) / SEGS;
    const int i0  = seg * per;
    const int i1  = min(N, i0 + per);

    float r = 0.f, rx0 = 0.f, ry0 = 0.f;
    if (j < M) {
        float2 xj = x[j];
        float  b  = bw[j];
        r   = sqrtf(LOG2E / (2.0f * b * b));
        rx0 = r * xj.x;
        ry0 = r * xj.y;
    }

    // dual accumulators: independent chains for ILP / v_pk_fma_f32
    float num0 = 0.f, num1 = 0.f, den0 = 0.f, den1 = 0.f;
    int i = i0;
    #pragma unroll 8
    for (; i + 1 < i1; i += 2) {
        float2 pa = inputs[i];       // block-uniform -> scalar load
        float2 pb = inputs[i + 1];
        float  oa = outputs[i];
        float  ob = outputs[i + 1];
        float dxa = fmaf(r, pa.x, -rx0);
        float dya = fmaf(r, pa.y, -ry0);
        float dxb = fmaf(r, pb.x, -rx0);
        float dyb = fmaf(r, pb.y, -ry0);
        float ta  = fmaf(dxa, dxa, dya * dya);
        float tb  = fmaf(dxb, dxb, dyb * dyb);
        float wa  = __builtin_amdgcn_exp2f(-ta);
        float wb  = __builtin_amdgcn_exp2f(-tb);
        num0 = fmaf(wa, oa, num0);
        num1 = fmaf(wb, ob, num1);
        den0 += wa;
        den1 += wb;
    }
    if (i < i1) {  // odd tail
        float2 pa = inputs[i];
        float  oa = outputs[i];
        float dxa = fmaf(r, pa.x, -rx0);
        float dya = fmaf(r, pa.y, -ry0);
        float ta  = fmaf(dxa, dxa, dya * dya);
        float wa  = __builtin_amdgcn_exp2f(-ta);
        num0 = fmaf(wa, oa, num0);
        den0 += wa;
    }

    if (j < M) partial[(size_t)seg * M + j] = make_float2(num0 + num1, den0 + den1);
}

// Kernel 2: reduce the SEGS partials per output and normalize.
// Fully unrolled -> 64 independent dwordx2 loads in flight per thread.
__global__ __launch_bounds__(BLOCK) void nw_finalize(
    const float2* __restrict__ partial,
    float*        __restrict__ out,
    int M)
{
    const int j = blockIdx.x * BLOCK + threadIdx.x;
    if (j >= M) return;
    float num = 0.f, den = 0.f;
    #pragma unroll
    for (int s = 0; s < SEGS; ++s) {
        float2 p = partial[(size_t)s * M + j];   // coalesced across j
        num += p.x;
        den += p.y;
    }
    out[j] = num / (den + EPS);
}

extern "C" void kernel_launch(void* const* d_in, const int* in_sizes, int n_in,
                              void* d_out, int out_size, void* d_ws, size_t ws_size,
                              hipStream_t stream) {
    // setup_inputs() dict order: x (M*2), inputs (N*2), outputs (N), bandwidth (M)
    const float2* x       = (const float2*)d_in[0];
    const float2* inputs  = (const float2*)d_in[1];
    const float*  outputs = (const float*) d_in[2];
    const float*  bwv     = (const float*) d_in[3];
    const int N = in_sizes[2];   // outputs element count
    const int M = in_sizes[3];   // bandwidth element count
    float*        out     = (float*)d_out;
    float2*       partial = (float2*)d_ws;   // SEGS * M * 8 B = 4 MB

    dim3 grid1((M + BLOCK - 1) / BLOCK, SEGS);
    nw_partial<<<grid1, BLOCK, 0, stream>>>(x, inputs, outputs, bwv, partial, N, M);

    nw_finalize<<<dim3((M + BLOCK - 1) / BLOCK), BLOCK, 0, stream>>>(partial, out, M);
}